// Round 1
// baseline (1132.218 us; speedup 1.0000x reference)
//
#include <hip/hip_runtime.h>
#include <math.h>

// Problem dims (from reference): B=64, L=512, P=2048, EDIM=256 (= 2 comp x 128)
#define LSEQ 512
#define EDIM 256
#define PBLK 16   // positions per block
#define NPW  4    // positions per wave (PBLK / 4 waves)

// ---------------- precompute: sinusoidal PE table (L x EDIM) ----------------
__global__ void precompute_pe(float* __restrict__ pe) {
    int l = blockIdx.x;        // 0..511
    int j = threadIdx.x;       // 0..127  pair index
    // div_j = exp(2j * (-ln(10000)/256)); ang = l * div_j
    float div = expf((2.0f * (float)j) * (-logf(10000.0f) / 256.0f));
    float ang = (float)l * div;
    // accurate sinf/cosf: ang can be up to ~511 rad, fast-path range reduction unsafe
    pe[l * EDIM + 2 * j]     = sinf(ang);
    pe[l * EDIM + 2 * j + 1] = cosf(ang);
}

// ------------- precompute: per-(b,l) {1/width, amplitude, row offset} -------
__global__ void precompute_params(const int* __restrict__ bs,
                                  const float* __restrict__ ls,
                                  float4* __restrict__ params, int n) {
    int i = blockIdx.x * 256 + threadIdx.x;
    if (i >= n) return;
    int byte = bs[i];
    float l1 = ls[byte * 3 + 1];
    float l2 = ls[byte * 3 + 2];
    float wdt = fabsf(l1) * 0.02f + 1e-5f;
    float amp = 1.0f / (1.0f + expf(-l2));        // sigmoid
    params[i] = make_float4(1.0f / wdt, amp, __int_as_float(byte * EDIM), 0.0f);
}

// ----------------------------- main field kernel ----------------------------
// Grid: B * (P/PBLK) blocks of 256 threads (4 waves).
// Each wave owns NPW consecutive p's; lanes span the 256 dims (4 dims/lane).
// The per-l "in range" test depends only on (b,p,l) -> wave-uniform branch.
__global__ __launch_bounds__(256) void field_main(
    const float* __restrict__ cpos,    // (B,P)
    const float* __restrict__ emb,     // (256, EDIM)
    const float* __restrict__ pe,      // (L, EDIM)
    const float4* __restrict__ params, // (B, L) {winv, amp, rowoff, -}
    float* __restrict__ out,           // (B, P, EDIM)
    int B, int P) {
    const int nPblk = P / PBLK;
    const int b     = blockIdx.x / nPblk;
    const int pbase = (blockIdx.x % nPblk) * PBLK + (int)(threadIdx.x >> 6) * NPW;
    const int d0    = ((int)threadIdx.x & 63) << 2;

    float pos[NPW];
#pragma unroll
    for (int i = 0; i < NPW; ++i) pos[i] = cpos[(size_t)b * P + pbase + i];

    float4 acc[NPW];
#pragma unroll
    for (int i = 0; i < NPW; ++i) acc[i] = make_float4(0.f, 0.f, 0.f, 0.f);

    const float invL = 1.0f / (float)(LSEQ - 1);
    const float4* prm = params + (size_t)b * LSEQ;

    for (int l = 0; l < LSEQ; ++l) {
        float4 q = prm[l];                 // uniform across wave (L1-hit broadcast)
        float bl = (float)l * invL;
        float w[NPW];
        bool any = false;
#pragma unroll
        for (int i = 0; i < NPW; ++i) {
            float t = (pos[i] - bl) * q.x;
            float s = t * t;
            if (s < 36.0f) {               // exp(-18) ~ 1.5e-8: negligible beyond
                w[i] = q.y * __expf(-0.5f * s);
                any = true;
            } else {
                w[i] = 0.0f;
            }
        }
        if (any) {                          // wave-uniform branch
            int ro = __float_as_int(q.z);
            float4 ea = *(const float4*)(emb + ro + d0);
            float4 pv = *(const float4*)(pe + (size_t)l * EDIM + d0);
            float bx = ea.x + pv.x, by = ea.y + pv.y;
            float bz = ea.z + pv.z, bw = ea.w + pv.w;
#pragma unroll
            for (int i = 0; i < NPW; ++i) {
                acc[i].x = fmaf(w[i], bx, acc[i].x);
                acc[i].y = fmaf(w[i], by, acc[i].y);
                acc[i].z = fmaf(w[i], bz, acc[i].z);
                acc[i].w = fmaf(w[i], bw, acc[i].w);
            }
        }
    }

#pragma unroll
    for (int i = 0; i < NPW; ++i) {
        size_t o = ((size_t)b * P + (pbase + i)) * EDIM + d0;
        *(float4*)(out + o) = acc[i];
    }
}

extern "C" void kernel_launch(void* const* d_in, const int* in_sizes, int n_in,
                              void* d_out, int out_size, void* d_ws, size_t ws_size,
                              hipStream_t stream) {
    const int*   bs   = (const int*)d_in[0];    // byte_sequence (B,L)
    const float* cpos = (const float*)d_in[1];  // continuous_positions (B,P)
    const float* emb  = (const float*)d_in[2];  // emb_table (256, EDIM)
    const float* ls   = (const float*)d_in[3];  // locality_shapes (256, 3)

    const int B = in_sizes[0] / LSEQ;           // 64
    const int P = in_sizes[1] / B;              // 2048

    float*  pe     = (float*)d_ws;                                   // 512 KB
    float4* params = (float4*)((char*)d_ws + (size_t)LSEQ * EDIM * 4); // 512 KB

    precompute_pe<<<LSEQ, EDIM / 2, 0, stream>>>(pe);
    precompute_params<<<(B * LSEQ + 255) / 256, 256, 0, stream>>>(bs, ls, params, B * LSEQ);
    field_main<<<B * (P / PBLK), 256, 0, stream>>>(cpos, emb, pe, params,
                                                   (float*)d_out, B, P);
}

// Round 2
// 195.827 us; speedup vs baseline: 5.7817x; 5.7817x over previous
//
#include <hip/hip_runtime.h>
#include <math.h>

#define LSEQ 512
#define EDIM 256
#define PDIM 2048

typedef short bf16x8 __attribute__((ext_vector_type(8)));
typedef short bf16x4 __attribute__((ext_vector_type(4)));
typedef float f32x4  __attribute__((ext_vector_type(4)));

__device__ inline unsigned short f2bf(float x) {
    union { float f; unsigned u; } v; v.f = x;
    unsigned r = v.u + 0x7fffu + ((v.u >> 16) & 1u);  // RNE
    return (unsigned short)(r >> 16);
}
__device__ inline float bf2f(unsigned short h) {
    union { float f; unsigned u; } v; v.u = ((unsigned)h) << 16;
    return v.f;
}

// ---------------- precompute: sinusoidal PE table (L x EDIM) fp32 ------------
__global__ void precompute_pe(float* __restrict__ pe) {
    int l = blockIdx.x;
    int j = threadIdx.x;           // 0..127 pair index
    float div = expf((2.0f * (float)j) * (-logf(10000.0f) / 256.0f));
    float ang = (float)l * div;
    pe[l * EDIM + 2 * j]     = sinf(ang);
    pe[l * EDIM + 2 * j + 1] = cosf(ang);
}

// ------------- precompute: per-(b,l) {1/width, amplitude} -------------------
__global__ void precompute_params(const int* __restrict__ bs,
                                  const float* __restrict__ ls,
                                  float4* __restrict__ params, int n) {
    int i = blockIdx.x * 256 + threadIdx.x;
    if (i >= n) return;
    int byte = bs[i];
    float l1 = ls[byte * 3 + 1];
    float l2 = ls[byte * 3 + 2];
    float wdt = fabsf(l1) * 0.02f + 1e-5f;
    float amp = 1.0f / (1.0f + expf(-l2));
    params[i] = make_float4(1.0f / wdt, amp, 0.0f, 0.0f);
}

// ----------------------------- MFMA field kernel ----------------------------
// Block: 512 thr (8 waves, 2 prow x 4 ecol). Tile: 128p x 128e, BK=64, K=512.
// out = W(2048x512) @ BASE(512x256) per b, 3-product bf16 hi/lo split.
__global__ __launch_bounds__(512, 4) void field_mfma(
    const int*    __restrict__ bs,     // (B, L)
    const float*  __restrict__ cpos,   // (B, P)
    const float*  __restrict__ emb,    // (256, E)
    const float*  __restrict__ pe,     // (L, E)
    const float4* __restrict__ params, // (B, L) {winv, amp}
    float*        __restrict__ out) {  // (B, P, E)

    // LDS tiles: row-major [row][64] bf16, 128B rows, slot-XOR swizzle (row&7)
    __shared__ __align__(16) short sWh[128 * 64], sWl[128 * 64];
    __shared__ __align__(16) short sBh[128 * 64], sBl[128 * 64];
    __shared__ float sPos[128];

    const int bid = blockIdx.x;
    const int et  = bid & 1;
    const int pt  = (bid >> 1) & 15;
    const int b   = bid >> 5;
    const int tid = threadIdx.x;
    const int lane = tid & 63, wave = tid >> 6;

    if (tid < 128) sPos[tid] = cpos[b * PDIM + pt * 128 + tid];

    // staging maps
    const int se  = tid & 127;       // BASE: local e row
    const int slh = tid >> 7;        // BASE: l-quarter (0..3)
    const int ge  = et * 128 + se;   // global e
    const int kg  = tid & 15;        // W: k-group (4 l's)
    const int pg  = tid >> 4;        // W: p-group (4 p's)

    // compute maps
    const int c15 = lane & 15, g4 = lane >> 4;
    const int wrow = wave >> 2, wcol = wave & 3;

    f32x4 acc[4][2];
#pragma unroll
    for (int i = 0; i < 4; ++i)
#pragma unroll
        for (int j = 0; j < 2; ++j) acc[i][j] = (f32x4)(0.f);

    __syncthreads();
    float mypos[4];
#pragma unroll
    for (int j = 0; j < 4; ++j) mypos[j] = sPos[pg * 4 + j];

    const float invL = 1.0f / (float)(LSEQ - 1);

    for (int ks = 0; ks < 8; ++ks) {
        const int kbase = ks * 64;

        // ---- stage BASE: thread = one e, 16 l's ----
#pragma unroll
        for (int ch = 0; ch < 2; ++ch) {
            const int l0 = kbase + slh * 16 + ch * 8;
            bf16x8 hv, lv;
#pragma unroll
            for (int j = 0; j < 8; ++j) {
                int l = l0 + j;
                int byte = bs[b * LSEQ + l];
                float v = emb[byte * EDIM + ge] + pe[l * EDIM + ge];
                unsigned short h = f2bf(v);
                hv[j] = (short)h;
                lv[j] = (short)f2bf(v - bf2f(h));
            }
            const int slot = (slh * 2 + ch) ^ (se & 7);
            const int off  = se * 64 + slot * 8;
            *(bf16x8*)&sBh[off] = hv;
            *(bf16x8*)&sBl[off] = lv;
        }

        // ---- stage W: thread = 4 p x 4 l ----
        {
            const int k0 = kbase + kg * 4;
            const float4 q0 = params[b * LSEQ + k0 + 0];
            const float4 q1 = params[b * LSEQ + k0 + 1];
            const float4 q2 = params[b * LSEQ + k0 + 2];
            const float4 q3 = params[b * LSEQ + k0 + 3];
            const float bl0 = (float)(k0 + 0) * invL;
            const float bl1 = (float)(k0 + 1) * invL;
            const float bl2 = (float)(k0 + 2) * invL;
            const float bl3 = (float)(k0 + 3) * invL;
#pragma unroll
            for (int j = 0; j < 4; ++j) {
                const int p = pg * 4 + j;
                const float pos = mypos[j];
                float w0, w1, w2, w3;
                { float t = (pos - bl0) * q0.x; w0 = q0.y * __expf(-0.5f * t * t); }
                { float t = (pos - bl1) * q1.x; w1 = q1.y * __expf(-0.5f * t * t); }
                { float t = (pos - bl2) * q2.x; w2 = q2.y * __expf(-0.5f * t * t); }
                { float t = (pos - bl3) * q3.x; w3 = q3.y * __expf(-0.5f * t * t); }
                bf16x4 hv, lv;
                unsigned short h;
                h = f2bf(w0); hv[0] = (short)h; lv[0] = (short)f2bf(w0 - bf2f(h));
                h = f2bf(w1); hv[1] = (short)h; lv[1] = (short)f2bf(w1 - bf2f(h));
                h = f2bf(w2); hv[2] = (short)h; lv[2] = (short)f2bf(w2 - bf2f(h));
                h = f2bf(w3); hv[3] = (short)h; lv[3] = (short)f2bf(w3 - bf2f(h));
                const int slot = (kg >> 1) ^ (p & 7);
                const int off  = p * 64 + slot * 8 + (kg & 1) * 4;
                *(bf16x4*)&sWh[off] = hv;
                *(bf16x4*)&sWl[off] = lv;
            }
        }
        __syncthreads();

        // ---- compute: 2 kk x (4 rt x 2 ct x 3 products) ----
#pragma unroll
        for (int kk = 0; kk < 2; ++kk) {
            bf16x8 ah[4], al[4];
#pragma unroll
            for (int rt = 0; rt < 4; ++rt) {
                const int row  = wrow * 64 + rt * 16 + c15;
                const int slot = (kk * 4 + g4) ^ (row & 7);
                const int off  = row * 64 + slot * 8;
                ah[rt] = *(const bf16x8*)&sWh[off];
                al[rt] = *(const bf16x8*)&sWl[off];
            }
#pragma unroll
            for (int ct = 0; ct < 2; ++ct) {
                const int erow = wcol * 32 + ct * 16 + c15;
                const int slot = (kk * 4 + g4) ^ (erow & 7);
                const int off  = erow * 64 + slot * 8;
                const bf16x8 bh = *(const bf16x8*)&sBh[off];
                const bf16x8 bl = *(const bf16x8*)&sBl[off];
#pragma unroll
                for (int rt = 0; rt < 4; ++rt) {
                    acc[rt][ct] = __builtin_amdgcn_mfma_f32_16x16x32_bf16(ah[rt], bh, acc[rt][ct], 0, 0, 0);
                    acc[rt][ct] = __builtin_amdgcn_mfma_f32_16x16x32_bf16(ah[rt], bl, acc[rt][ct], 0, 0, 0);
                    acc[rt][ct] = __builtin_amdgcn_mfma_f32_16x16x32_bf16(al[rt], bh, acc[rt][ct], 0, 0, 0);
                }
            }
        }
        __syncthreads();
    }

    // ---- epilogue: C/D layout col=lane&15, row=(lane>>4)*4+reg ----
#pragma unroll
    for (int rt = 0; rt < 4; ++rt)
#pragma unroll
        for (int ct = 0; ct < 2; ++ct) {
            const int e = et * 128 + wcol * 32 + ct * 16 + c15;
#pragma unroll
            for (int r = 0; r < 4; ++r) {
                const int p = pt * 128 + wrow * 64 + rt * 16 + g4 * 4 + r;
                out[((size_t)b * PDIM + p) * EDIM + e] = acc[rt][ct][r];
            }
        }
}

extern "C" void kernel_launch(void* const* d_in, const int* in_sizes, int n_in,
                              void* d_out, int out_size, void* d_ws, size_t ws_size,
                              hipStream_t stream) {
    const int*   bs   = (const int*)d_in[0];
    const float* cpos = (const float*)d_in[1];
    const float* emb  = (const float*)d_in[2];
    const float* ls   = (const float*)d_in[3];

    const int B = in_sizes[0] / LSEQ;   // 64

    float*  pe     = (float*)d_ws;                                     // 512 KB
    float4* params = (float4*)((char*)d_ws + (size_t)LSEQ * EDIM * 4); // 512 KB

    precompute_pe<<<LSEQ, EDIM / 2, 0, stream>>>(pe);
    precompute_params<<<(B * LSEQ + 255) / 256, 256, 0, stream>>>(bs, ls, params, B * LSEQ);

    const int nblocks = B * (PDIM / 128) * (EDIM / 128);  // 64*16*2 = 2048
    field_mfma<<<nblocks, 512, 0, stream>>>(bs, cpos, emb, pe, params, (float*)d_out);
}

// Round 3
// 75.501 us; speedup vs baseline: 14.9960x; 2.5937x over previous
//
#include <hip/hip_runtime.h>
#include <math.h>

#define LSEQ 512
#define EDIM 256
#define PDIM 2048
#define BM   128

typedef _Float16 f16x8 __attribute__((ext_vector_type(8)));
typedef _Float16 f16x4 __attribute__((ext_vector_type(4)));
typedef float    f32x4 __attribute__((ext_vector_type(4)));

__device__ inline void g2lds16(const void* g, void* l) {
    __builtin_amdgcn_global_load_lds(
        (const __attribute__((address_space(1))) void*)g,
        (__attribute__((address_space(3))) void*)l, 16, 0, 0);
}

// ---------------- precompute: sinusoidal PE table (L x EDIM) fp32 ------------
__global__ void precompute_pe(float* __restrict__ pe) {
    int l = blockIdx.x;
    int j = threadIdx.x;           // 0..127 pair index
    float div = expf((2.0f * (float)j) * (-logf(10000.0f) / 256.0f));
    float ang = (float)l * div;
    pe[l * EDIM + 2 * j]     = sinf(ang);
    pe[l * EDIM + 2 * j + 1] = cosf(ang);
}

// ------------- precompute: per-(b,l) {1/width, amplitude} -------------------
__global__ void precompute_params(const int* __restrict__ bs,
                                  const float* __restrict__ ls,
                                  float4* __restrict__ params, int n) {
    int i = blockIdx.x * 256 + threadIdx.x;
    if (i >= n) return;
    int byte = bs[i];
    float l1 = ls[byte * 3 + 1];
    float l2 = ls[byte * 3 + 2];
    float wdt = fabsf(l1) * 0.02f + 1e-5f;
    float amp = 1.0f / (1.0f + expf(-l2));
    params[i] = make_float4(1.0f / wdt, amp, 0.0f, 0.0f);
}

// ------- precompute: BASE^T fp16, pre-swizzled LDS tile image ---------------
// Layout: baset[b][ks][e 0..255][slot 0..7][j 0..7], slot s holds l-group
// g = s ^ (e&7), l = ks*64 + g*8 + j. Row = 64 fp16 = 128 B.
__global__ void precompute_baset(const int* __restrict__ bs,
                                 const float* __restrict__ emb,
                                 const float* __restrict__ pe,
                                 _Float16* __restrict__ baset) {
    const int b  = blockIdx.x >> 3;
    const int ks = blockIdx.x & 7;
    const int e  = threadIdx.x;            // 0..255
    const int kbase = ks * 64;
    _Float16* row = baset + ((size_t)(b * 8 + ks) * 256 + e) * 64;
#pragma unroll
    for (int g = 0; g < 8; ++g) {
        f16x8 v;
#pragma unroll
        for (int j = 0; j < 8; ++j) {
            const int l = kbase + g * 8 + j;
            const int byte = bs[b * LSEQ + l];
            v[j] = (_Float16)(emb[byte * EDIM + e] + pe[l * EDIM + e]);
        }
        const int slot = g ^ (e & 7);
        *(f16x8*)&row[slot * 8] = v;
    }
}

// ----------------------------- MFMA field kernel ----------------------------
// Block: 512 thr (8 waves, 2 prow x 4 ecol). Tile: 128p x 256e, BK=64, K=512.
// out[b] = W(2048x512) @ BASE(512x256), fp16 single product, fp32 accum.
__global__ __launch_bounds__(512, 4) void field_mfma(
    const float*    __restrict__ cpos,    // (B, P)
    const float4*   __restrict__ params,  // (B, L) {winv, amp}
    const _Float16* __restrict__ baset,   // pre-swizzled BASE^T
    float*          __restrict__ out) {   // (B, P, E)

    __shared__ __align__(16) _Float16 sW[BM * 64];    // 16 KB
    __shared__ __align__(16) _Float16 sB[256 * 64];   // 32 KB
    __shared__ float sPos[BM];

    // bijective XCD-aware swizzle (1024 blocks, 1024%8==0)
    const int orig = blockIdx.x;
    const int wg   = (orig & 7) * 128 + (orig >> 3);
    const int b    = wg >> 4;
    const int pt   = wg & 15;

    const int tid = threadIdx.x, lane = tid & 63, wave = tid >> 6;
    if (tid < BM) sPos[tid] = cpos[b * PDIM + pt * BM + tid];

    const int kg = tid & 15, pg = tid >> 4;       // W staging map
    const int c15 = lane & 15, g4 = lane >> 4;    // MFMA lane map
    const int wrow = wave >> 2, wcol = wave & 3;  // 2 x 4 wave grid

    f32x4 acc[4][4];
#pragma unroll
    for (int i = 0; i < 4; ++i)
#pragma unroll
        for (int j = 0; j < 4; ++j) acc[i][j] = (f32x4)(0.f);

    __syncthreads();
    float mypos[4];
#pragma unroll
    for (int j = 0; j < 4; ++j) mypos[j] = sPos[pg * 4 + j];

    const float invL = 1.0f / (float)(LSEQ - 1);
    const float4* prm = params + b * LSEQ;
    const _Float16* bt = baset + (size_t)b * 8 * 256 * 64;

    for (int ks = 0; ks < 8; ++ks) {
        // ---- stage BASE tile: 32 KB contiguous, global_load_lds width 16 ----
        const _Float16* src = bt + ks * (256 * 64);
#pragma unroll
        for (int is = 0; is < 4; ++is) {
            g2lds16(src + is * 4096 + wave * 512 + lane * 8,
                    sB  + is * 4096 + wave * 512);
        }

        // ---- stage W: thread = 4 p x 4 l, fp16 ----
        {
            const int k0 = ks * 64 + kg * 4;
            const float4 q0 = prm[k0 + 0];
            const float4 q1 = prm[k0 + 1];
            const float4 q2 = prm[k0 + 2];
            const float4 q3 = prm[k0 + 3];
            const float bl0 = (float)(k0 + 0) * invL;
            const float bl1 = (float)(k0 + 1) * invL;
            const float bl2 = (float)(k0 + 2) * invL;
            const float bl3 = (float)(k0 + 3) * invL;
#pragma unroll
            for (int j = 0; j < 4; ++j) {
                const int p = pg * 4 + j;
                const float pos = mypos[j];
                f16x4 v;
                { float t = (pos - bl0) * q0.x; v[0] = (_Float16)(q0.y * __expf(-0.5f * t * t)); }
                { float t = (pos - bl1) * q1.x; v[1] = (_Float16)(q1.y * __expf(-0.5f * t * t)); }
                { float t = (pos - bl2) * q2.x; v[2] = (_Float16)(q2.y * __expf(-0.5f * t * t)); }
                { float t = (pos - bl3) * q3.x; v[3] = (_Float16)(q3.y * __expf(-0.5f * t * t)); }
                const int off = p * 64 + ((kg >> 1) ^ (p & 7)) * 8 + (kg & 1) * 4;
                *(f16x4*)&sW[off] = v;
            }
        }
        __syncthreads();   // compiler emits vmcnt(0)+lgkmcnt(0) drain here

        // ---- compute: 2 kk x (4 rt x 4 ct) MFMA ----
#pragma unroll
        for (int kk = 0; kk < 2; ++kk) {
            f16x8 af[4];
#pragma unroll
            for (int rt = 0; rt < 4; ++rt) {
                const int row = wrow * 64 + rt * 16 + c15;
                const int off = row * 64 + (((kk * 4 + g4) ^ (row & 7)) * 8);
                af[rt] = *(const f16x8*)&sW[off];
            }
#pragma unroll
            for (int ct = 0; ct < 4; ++ct) {
                const int erow = wcol * 64 + ct * 16 + c15;
                const int off  = erow * 64 + (((kk * 4 + g4) ^ (erow & 7)) * 8);
                const f16x8 bf = *(const f16x8*)&sB[off];
#pragma unroll
                for (int rt = 0; rt < 4; ++rt)
                    acc[rt][ct] = __builtin_amdgcn_mfma_f32_16x16x32_f16(af[rt], bf, acc[rt][ct], 0, 0, 0);
            }
        }
        __syncthreads();
    }

    // ---- epilogue: C/D layout col=lane&15 (e), row=(lane>>4)*4+reg (p) ----
#pragma unroll
    for (int rt = 0; rt < 4; ++rt)
#pragma unroll
        for (int ct = 0; ct < 4; ++ct) {
            const int e = wcol * 64 + ct * 16 + c15;
#pragma unroll
            for (int r = 0; r < 4; ++r) {
                const int p = pt * BM + wrow * 64 + rt * 16 + g4 * 4 + r;
                out[((size_t)b * PDIM + p) * EDIM + e] = acc[rt][ct][r];
            }
        }
}

extern "C" void kernel_launch(void* const* d_in, const int* in_sizes, int n_in,
                              void* d_out, int out_size, void* d_ws, size_t ws_size,
                              hipStream_t stream) {
    const int*   bs   = (const int*)d_in[0];
    const float* cpos = (const float*)d_in[1];
    const float* emb  = (const float*)d_in[2];
    const float* ls   = (const float*)d_in[3];

    const int B = in_sizes[0] / LSEQ;   // 64

    char* ws = (char*)d_ws;
    float*     pe     = (float*)ws;                          // 512 KB
    float4*    params = (float4*)(ws + (1u << 19));          // 512 KB
    _Float16*  baset  = (_Float16*)(ws + (1u << 20));        // 16.8 MB

    precompute_pe<<<LSEQ, EDIM / 2, 0, stream>>>(pe);
    precompute_params<<<(B * LSEQ + 255) / 256, 256, 0, stream>>>(bs, ls, params, B * LSEQ);
    precompute_baset<<<B * 8, 256, 0, stream>>>(bs, emb, pe, baset);

    const int nblocks = B * (PDIM / BM);  // 1024
    field_mfma<<<nblocks, 512, 0, stream>>>(cpos, params, baset, (float*)d_out);
}

// Round 4
// 73.959 us; speedup vs baseline: 15.3088x; 1.0209x over previous
//
#include <hip/hip_runtime.h>
#include <math.h>

#define LSEQ 512
#define EDIM 256
#define PDIM 2048
#define BM   128
#define BK   32
#define NT   16      // K-steps = LSEQ/BK

typedef _Float16 f16x8 __attribute__((ext_vector_type(8)));
typedef float    f32x4 __attribute__((ext_vector_type(4)));

// Conflict-free interleaved tile layout (fp16 element offset) for a
// [rows][32] fp16 tile stored as 128B row-pairs. r = row, g = l-group (0..3).
// All 64 lanes of a frag ds_read_b128 spread uniformly over banks (8/slot).
__device__ __host__ inline int tile_off(int r, int g) {
    return ((r >> 1) << 6) + ((r & 1) << 5) + (((g ^ ((r >> 1) & 3)) & 3) << 3);
}

__device__ inline void g2lds16(const void* g, void* l) {
    __builtin_amdgcn_global_load_lds(
        (const __attribute__((address_space(1))) void*)g,
        (__attribute__((address_space(3))) void*)l, 16, 0, 0);
}

// ---- fused precompute: PE table (fp32) + per-(b,l) params {c2, amp} --------
__global__ void precompute_tables(const float* __restrict__ ls,
                                  const int* __restrict__ bs,
                                  float* __restrict__ pe,
                                  float2* __restrict__ params, int nparams) {
    const int bid = blockIdx.x, tid = threadIdx.x;
    if (bid < LSEQ) {
        if (tid < 128) {
            float div = expf((2.0f * (float)tid) * (-logf(10000.0f) / 256.0f));
            float ang = (float)bid * div;
            pe[bid * EDIM + 2 * tid]     = sinf(ang);   // accurate: ang up to 511 rad
            pe[bid * EDIM + 2 * tid + 1] = cosf(ang);
        }
    } else {
        const int i = (bid - LSEQ) * 256 + tid;
        if (i < nparams) {
            const int byte = bs[i];
            const float l1 = ls[byte * 3 + 1];
            const float l2 = ls[byte * 3 + 2];
            const float wdt = fabsf(l1) * 0.02f + 1e-5f;
            params[i] = make_float2(-0.5f / (wdt * wdt),            // c2
                                    1.0f / (1.0f + __expf(-l2)));   // amp
        }
    }
}

// ---- precompute BASE^T fp16 in the exact pre-swizzled LDS tile image -------
// chunk (b,t) = 16KB: B[e][l = t*32 + g*8 + j] at tile_off(e,g)+j
__global__ void precompute_baset(const int* __restrict__ bs,
                                 const float* __restrict__ emb,
                                 const float* __restrict__ pe,
                                 _Float16* __restrict__ baset) {
    const int b = blockIdx.x >> 4;
    const int t = blockIdx.x & 15;
    const int e = threadIdx.x;                         // 0..255
    const int* bsb = bs + b * LSEQ + t * BK;
    _Float16* chunk = baset + ((size_t)(b * NT + t) << 13);
#pragma unroll
    for (int g = 0; g < 4; ++g) {
        f16x8 v;
#pragma unroll
        for (int j = 0; j < 8; ++j) {
            const int l = t * BK + g * 8 + j;
            const int byte = bsb[g * 8 + j];
            v[j] = (_Float16)(emb[byte * EDIM + e] + pe[l * EDIM + e]);
        }
        *(f16x8*)&chunk[tile_off(e, g)] = v;
    }
}

// ----------------------------- MFMA field kernel ----------------------------
// 512 thr (8 waves, 2x4). Tile 128p x 256e, BK=32, 16 K-steps, 2-phase dbuf.
__global__ __launch_bounds__(512, 4) void field_mfma(
    const float*    __restrict__ cpos,    // (B,P)
    const float2*   __restrict__ params,  // (B,L) {c2, amp}
    const _Float16* __restrict__ baset,   // pre-swizzled BASE^T chunks
    float*          __restrict__ out) {   // (B,P,E)

    __shared__ __align__(16) _Float16 sW[2][BM * BK];    // 2 x 8 KB
    __shared__ __align__(16) _Float16 sB[2][EDIM * BK];  // 2 x 16 KB
    __shared__ __align__(16) float2   sPrm[LSEQ];        // 4 KB

    const int orig = blockIdx.x;
    const int wg   = (orig & 7) * 128 + (orig >> 3);     // bijective XCD swizzle
    const int b    = wg >> 4;
    const int pt   = wg & 15;

    const int tid = threadIdx.x, lane = tid & 63, wave = tid >> 6;
    const int c15 = lane & 15, g4 = lane >> 4;
    const int wrow = wave >> 2, wcol = wave & 3;

    // W-gen role: thread -> (p row, l-group)
    const int sp = tid >> 2;
    const int sg = tid & 3;
    const float mypos = cpos[b * PDIM + pt * BM + sp];
    const float invL  = 1.0f / (float)(LSEQ - 1);
    const int   woff  = tile_off(sp, sg);

    // frag read offsets (per-thread constants)
    int aoff[4], boff[4];
#pragma unroll
    for (int rt = 0; rt < 4; ++rt) aoff[rt] = tile_off(wrow * 64 + rt * 16 + c15, g4);
#pragma unroll
    for (int ct = 0; ct < 4; ++ct) boff[ct] = tile_off(wcol * 64 + ct * 16 + c15, g4);

    // ---- prologue: params -> LDS; issue B0,B1 gloads ----
    sPrm[tid] = params[b * LSEQ + tid];
    const _Float16* bt = baset + ((size_t)b * NT << 13);
#pragma unroll
    for (int buf = 0; buf < 2; ++buf) {
        const _Float16* src = bt + buf * 8192 + wave * 1024 + lane * 8;
        g2lds16(src,       &sB[buf][wave * 1024]);
        g2lds16(src + 512, &sB[buf][wave * 1024 + 512]);
    }
    __syncthreads();

    // W generator for K-step t into buffer dbuf
    auto genW = [&](int t, int dbuf) {
        const float4* qp = (const float4*)&sPrm[t * BK + sg * 8];
        const float4 q01 = qp[0], q23 = qp[1], q45 = qp[2], q67 = qp[3];
        const float bl0 = (float)(t * BK + sg * 8) * invL;
        f16x8 wv;
#define GENW(i, c2, am) { float d = mypos - (bl0 + (float)(i) * invL); \
                          wv[i] = (_Float16)((am) * __expf(d * d * (c2))); }
        GENW(0, q01.x, q01.y) GENW(1, q01.z, q01.w)
        GENW(2, q23.x, q23.y) GENW(3, q23.z, q23.w)
        GENW(4, q45.x, q45.y) GENW(5, q45.z, q45.w)
        GENW(6, q67.x, q67.y) GENW(7, q67.z, q67.w)
#undef GENW
        *(f16x8*)&sW[dbuf][woff] = wv;
    };

    genW(0, 0);
    __syncthreads();

    f32x4 acc[4][4];
#pragma unroll
    for (int i = 0; i < 4; ++i)
#pragma unroll
        for (int j = 0; j < 4; ++j) acc[i][j] = (f32x4)(0.f);

    // ---- main loop: one barrier per K-step, B loads span a full iter ----
    for (int t = 0; t < NT; ++t) {
        const int cur = t & 1;
        if (t < NT - 1) genW(t + 1, cur ^ 1);   // writes spare buffer, no hazard

        const _Float16* wb = sW[cur];
        const _Float16* bb = sB[cur];
        f16x8 af[4];
#pragma unroll
        for (int rt = 0; rt < 4; ++rt) af[rt] = *(const f16x8*)&wb[aoff[rt]];
        __builtin_amdgcn_s_setprio(1);
#pragma unroll
        for (int ct = 0; ct < 4; ++ct) {
            const f16x8 bf = *(const f16x8*)&bb[boff[ct]];
#pragma unroll
            for (int rt = 0; rt < 4; ++rt)
                acc[rt][ct] = __builtin_amdgcn_mfma_f32_16x16x32_f16(af[rt], bf, acc[rt][ct], 0, 0, 0);
        }
        __builtin_amdgcn_s_setprio(0);

        __syncthreads();   // drains W[t+1] ds_writes + B[t+1] gloads (full iter old)

        if (t < NT - 2) {  // issue B[t+2] into the buffer just freed
            const _Float16* src = bt + (t + 2) * 8192 + wave * 1024 + lane * 8;
            g2lds16(src,       &sB[cur][wave * 1024]);
            g2lds16(src + 512, &sB[cur][wave * 1024 + 512]);
        }
    }

    // ---- epilogue: C/D layout col=lane&15 (e), row=(lane>>4)*4+reg (p) ----
#pragma unroll
    for (int rt = 0; rt < 4; ++rt)
#pragma unroll
        for (int ct = 0; ct < 4; ++ct) {
            const int e = wcol * 64 + ct * 16 + c15;
#pragma unroll
            for (int r = 0; r < 4; ++r) {
                const int p = pt * BM + wrow * 64 + rt * 16 + g4 * 4 + r;
                out[((size_t)b * PDIM + p) * EDIM + e] = acc[rt][ct][r];
            }
        }
}

extern "C" void kernel_launch(void* const* d_in, const int* in_sizes, int n_in,
                              void* d_out, int out_size, void* d_ws, size_t ws_size,
                              hipStream_t stream) {
    const int*   bs   = (const int*)d_in[0];
    const float* cpos = (const float*)d_in[1];
    const float* emb  = (const float*)d_in[2];
    const float* ls   = (const float*)d_in[3];

    const int B = in_sizes[0] / LSEQ;   // 64

    char* ws = (char*)d_ws;
    float*    pe     = (float*)ws;                    // 512 KB
    float2*   params = (float2*)(ws + (1u << 19));    // 256 KB
    _Float16* baset  = (_Float16*)(ws + (1u << 20));  // 16 MB

    const int nparams = B * LSEQ;
    precompute_tables<<<LSEQ + (nparams + 255) / 256, 256, 0, stream>>>(ls, bs, pe, params, nparams);
    precompute_baset<<<B * NT, 256, 0, stream>>>(bs, emb, pe, baset);
    field_mfma<<<B * (PDIM / BM), 512, 0, stream>>>(cpos, params, baset, (float*)d_out);
}

// Round 6
// 65.993 us; speedup vs baseline: 17.1568x; 1.1207x over previous
//
#include <hip/hip_runtime.h>
#include <math.h>

#define LSEQ 512
#define EDIM 256
#define PDIM 2048
#define BM   128
#define BK   32
#define NT   16      // K-steps = LSEQ/BK

typedef _Float16 f16x8 __attribute__((ext_vector_type(8)));
typedef _Float16 f16x2 __attribute__((ext_vector_type(2)));
typedef float    f32x4 __attribute__((ext_vector_type(4)));

#if __has_builtin(__builtin_amdgcn_exp2f)
#define EXP2F(x) __builtin_amdgcn_exp2f(x)
#else
#define EXP2F(x) __expf((x) * 0.6931471805599453f)
#endif

__device__ inline f16x2 pk2(float a, float b) {
#if __has_builtin(__builtin_amdgcn_cvt_pkrtz)
    return __builtin_bit_cast(f16x2, __builtin_amdgcn_cvt_pkrtz(a, b));
#else
    f16x2 r; r[0] = (_Float16)a; r[1] = (_Float16)b; return r;
#endif
}

// Conflict-free interleaved tile layout (fp16 element offset) for a
// [rows][32] fp16 tile stored as 128B row-pairs. r = row, g = l-group (0..3).
// All 64 lanes of a frag ds_read_b128 spread uniformly over banks (8/slot).
__device__ __host__ inline int tile_off(int r, int g) {
    return ((r >> 1) << 6) + ((r & 1) << 5) + (((g ^ ((r >> 1) & 3)) & 3) << 3);
}

__device__ inline void g2lds16(const void* g, void* l) {
    __builtin_amdgcn_global_load_lds(
        (const __attribute__((address_space(1))) void*)g,
        (__attribute__((address_space(3))) void*)l, 16, 0, 0);
}

// ---- fused precompute: one block per (b, k-step) baset chunk ---------------
// Also writes params[b, l] = {-0.5/w^2 * log2e, log2(amp)} for its 32 l's.
// PE computed inline (sinf/cosf accurate; ang up to 511 rad).
__global__ __launch_bounds__(256) void precompute_all(
    const int*   __restrict__ bs,      // (B, L)
    const float* __restrict__ ls,      // (256, 3)
    const float* __restrict__ emb,     // (256, E)
    float2*      __restrict__ params,  // (B, L)
    _Float16*    __restrict__ baset) { // (B*NT) chunks of 16 KB
    const int b   = blockIdx.x >> 4;
    const int t   = blockIdx.x & 15;
    const int tid = threadIdx.x;       // = e (0..255)

    __shared__ int sByte[BK];
    if (tid < BK) {
        const int l    = t * BK + tid;
        const int byte = bs[b * LSEQ + l];
        sByte[tid] = byte;
        const float l1  = ls[byte * 3 + 1];
        const float l2  = ls[byte * 3 + 2];
        const float wdt = fabsf(l1) * 0.02f + 1e-5f;
        const float amp = 1.0f / (1.0f + __expf(-l2));
        params[b * LSEQ + l] = make_float2(-0.72134752f / (wdt * wdt),  // -0.5*log2e/w^2
                                           __log2f(amp));
    }
    __syncthreads();

    // PE dim e: pair index e>>1, phase e&1 (0=sin, 1=cos)
    const float div = __expf((float)(tid >> 1) * (-2.0f * 9.210340372f / 256.0f));
    _Float16* chunk = baset + ((size_t)blockIdx.x << 13);
#pragma unroll
    for (int g = 0; g < 4; ++g) {
        f16x8 v;
#pragma unroll
        for (int j = 0; j < 8; ++j) {
            const int lj  = g * 8 + j;
            const float ang = (float)(t * BK + lj) * div;
            const float pev = (tid & 1) ? cosf(ang) : sinf(ang);
            v[j] = (_Float16)(emb[sByte[lj] * EDIM + tid] + pev);
        }
        *(f16x8*)&chunk[tile_off(tid, g)] = v;
    }
}

// ----------------------------- MFMA field kernel ----------------------------
// 512 thr (8 waves, 2x4). Tile 128p x 256e, BK=32, 16 K-steps, 2-phase dbuf.
__global__ __launch_bounds__(512, 4) void field_mfma(
    const float*    __restrict__ cpos,    // (B,P)
    const float2*   __restrict__ params,  // (B,L) {c2*log2e, log2(amp)}
    const _Float16* __restrict__ baset,   // pre-swizzled BASE^T chunks
    float*          __restrict__ out) {   // (B,P,E)

    __shared__ __align__(16) _Float16 sW[2][BM * BK];    // 2 x 8 KB
    __shared__ __align__(16) _Float16 sB[2][EDIM * BK];  // 2 x 16 KB
    __shared__ __align__(16) float2   sPrm[LSEQ];        // 4 KB

    const int orig = blockIdx.x;
    const int wg   = (orig & 7) * 128 + (orig >> 3);     // bijective XCD swizzle
    const int b    = wg >> 4;
    const int pt   = wg & 15;

    const int tid = threadIdx.x, lane = tid & 63, wave = tid >> 6;
    const int c15 = lane & 15, g4 = lane >> 4;
    const int wrow = wave >> 2, wcol = wave & 3;

    // W-gen role: thread -> (p row, l-group of 8)
    const int sp = tid >> 2;
    const int sg = tid & 3;
    const float mypos = cpos[b * PDIM + pt * BM + sp];
    const float invL  = 1.0f / (float)(LSEQ - 1);
    const int   woff  = tile_off(sp, sg);

    // frag read offsets (per-thread constants)
    int aoff[4], boff[4];
#pragma unroll
    for (int rt = 0; rt < 4; ++rt) aoff[rt] = tile_off(wrow * 64 + rt * 16 + c15, g4);
#pragma unroll
    for (int ct = 0; ct < 4; ++ct) boff[ct] = tile_off(wcol * 64 + ct * 16 + c15, g4);

    // ---- prologue: params -> LDS; issue B0,B1 gloads ----
    sPrm[tid] = params[b * LSEQ + tid];
    const _Float16* bt = baset + ((size_t)b * NT << 13);
#pragma unroll
    for (int buf = 0; buf < 2; ++buf) {
        const _Float16* src = bt + buf * 8192 + wave * 1024 + lane * 8;
        g2lds16(src,       &sB[buf][wave * 1024]);
        g2lds16(src + 512, &sB[buf][wave * 1024 + 512]);
    }
    __syncthreads();

    // W generator for K-step t into buffer dbuf:
    // w = 2^(d*d*c2l2 + log2amp), packed to fp16 via cvt_pkrtz
    auto genW = [&](int t, int dbuf) {
        const float4* qp = (const float4*)&sPrm[t * BK + sg * 8];
        const float4 q01 = qp[0], q23 = qp[1], q45 = qp[2], q67 = qp[3];
        const float bl0 = (float)(t * BK + sg * 8) * invL;
        float w[8];
#define GW(i, c2, la) { float d = mypos - (bl0 + (float)(i) * invL); \
                        w[i] = EXP2F(fmaf(d * d, (c2), (la))); }
        GW(0, q01.x, q01.y) GW(1, q01.z, q01.w)
        GW(2, q23.x, q23.y) GW(3, q23.z, q23.w)
        GW(4, q45.x, q45.y) GW(5, q45.z, q45.w)
        GW(6, q67.x, q67.y) GW(7, q67.z, q67.w)
#undef GW
        f16x8 wv;
        ((f16x2*)&wv)[0] = pk2(w[0], w[1]);
        ((f16x2*)&wv)[1] = pk2(w[2], w[3]);
        ((f16x2*)&wv)[2] = pk2(w[4], w[5]);
        ((f16x2*)&wv)[3] = pk2(w[6], w[7]);
        *(f16x8*)&sW[dbuf][woff] = wv;
    };

    genW(0, 0);
    __syncthreads();

    f32x4 acc[4][4];
#pragma unroll
    for (int i = 0; i < 4; ++i)
#pragma unroll
        for (int j = 0; j < 4; ++j) acc[i][j] = (f32x4)(0.f);

    // ---- main loop: one barrier per K-step, B loads span a full iter ----
    for (int t = 0; t < NT; ++t) {
        const int cur = t & 1;
        if (t < NT - 1) genW(t + 1, cur ^ 1);   // spare buffer, no hazard

        const _Float16* wb = sW[cur];
        const _Float16* bb = sB[cur];
        f16x8 af[4];
#pragma unroll
        for (int rt = 0; rt < 4; ++rt) af[rt] = *(const f16x8*)&wb[aoff[rt]];
        __builtin_amdgcn_s_setprio(1);
#pragma unroll
        for (int ct = 0; ct < 4; ++ct) {
            const f16x8 bf = *(const f16x8*)&bb[boff[ct]];
#pragma unroll
            for (int rt = 0; rt < 4; ++rt)
                acc[rt][ct] = __builtin_amdgcn_mfma_f32_16x16x32_f16(af[rt], bf, acc[rt][ct], 0, 0, 0);
        }
        __builtin_amdgcn_s_setprio(0);

        __syncthreads();   // drains W[t+1] ds_writes + B[t+1] gloads

        if (t < NT - 2) {  // issue B[t+2] into the buffer just freed
            const _Float16* src = bt + (t + 2) * 8192 + wave * 1024 + lane * 8;
            g2lds16(src,       &sB[cur][wave * 1024]);
            g2lds16(src + 512, &sB[cur][wave * 1024 + 512]);
        }
    }

    // ---- epilogue: C/D layout col=lane&15 (e), row=(lane>>4)*4+reg (p) ----
#pragma unroll
    for (int rt = 0; rt < 4; ++rt)
#pragma unroll
        for (int ct = 0; ct < 4; ++ct) {
            const int e = wcol * 64 + ct * 16 + c15;
#pragma unroll
            for (int r = 0; r < 4; ++r) {
                const int p = pt * BM + wrow * 64 + rt * 16 + g4 * 4 + r;
                out[((size_t)b * PDIM + p) * EDIM + e] = acc[rt][ct][r];
            }
        }
}

extern "C" void kernel_launch(void* const* d_in, const int* in_sizes, int n_in,
                              void* d_out, int out_size, void* d_ws, size_t ws_size,
                              hipStream_t stream) {
    const int*   bs   = (const int*)d_in[0];
    const float* cpos = (const float*)d_in[1];
    const float* emb  = (const float*)d_in[2];
    const float* ls   = (const float*)d_in[3];

    const int B = in_sizes[0] / LSEQ;   // 64

    char* ws = (char*)d_ws;
    float2*   params = (float2*)ws;                   // 256 KB
    _Float16* baset  = (_Float16*)(ws + (1u << 18));  // 16 MB

    precompute_all<<<B * NT, 256, 0, stream>>>(bs, ls, emb, params, baset);
    field_mfma<<<B * (PDIM / BM), 512, 0, stream>>>(cpos, params, baset, (float*)d_out);
}